// Round 12
// baseline (295.962 us; speedup 1.0000x reference)
//
#include <hip/hip_runtime.h>
#include <limits.h>

// CCL 8-connectivity on 4096x4096 binary image (prob > 0.5).
// Output: int32 labels, label = (min linear index in component) + 1, bg = 0.
//
// State: BLOCK-granular parent array P_blk (2048x2048 ints, keys are PIXEL
// indices; canonical key of a block = its min fg pixel; union-by-min => root
// key = component min pixel) + packed nibble mask bnib (4 bits per 2x2 block).
// Local: BKE LDS union-find per 128x128 tile -> P_blk + bnib.
// Border: R9's proven run-start-dedup link set, gating via bitmasks, unites
// on P_blk. Final: 8 px/thread, mask-gated memoized resolve -> d_out.

constexpr int HH = 4096;
constexpr int WW = 4096;
constexpr int NPIX = HH * WW;
constexpr int TILE = 128;
constexpr int BDIM = TILE / 2;        // 64 blocks per tile dim
constexpr int NBLK = BDIM * BDIM;     // 4096
constexpr int BW = WW / 2;            // 2048 block cols
constexpr int WPR = BW / 8;           // 256 bnib words per block row
constexpr int NBOUND = HH / TILE - 1; // 31 boundaries per family
constexpr int BTHREADS = NBOUND * (WW / 32);  // 3968 per family

// ------------------------------------- block-keyed global union-find ------
__device__ __forceinline__ int blkof(int key) {
    return ((key >> 13) << 11) | ((key & 4095) >> 1);
}

__device__ __forceinline__ int find_B(int* P, int key) {
    while (true) {
        int xb = blkof(key);
        int p = P[xb];
        if (p == key) return key;
        int gp = P[blkof(p)];
        if (gp == p) return p;
        atomicMin(&P[xb], gp);   // path halving (monotone => race-safe)
        key = gp;
    }
}

__device__ __forceinline__ void unite_B(int* P, int a, int b) {
    while (true) {
        a = find_B(P, a);
        b = find_B(P, b);
        if (a == b) return;
        if (a > b) { int t = a; a = b; b = t; }
        int old = atomicMin(&P[blkof(b)], a);
        if (old == b) return;
        b = old;
    }
}

// ------------------------------------------- LDS union-find on pixel keys -
__device__ __forceinline__ int lkey2b(int k) {
    return ((k >> 8) << 6) | ((k & 127) >> 1);
}

__device__ __forceinline__ int find_l(int* par, int bk) {
    while (true) {
        int xb = lkey2b(bk);
        int p = par[xb];
        if (p == bk) return bk;
        int pb = lkey2b(p);
        int gp = par[pb];
        if (gp == p) return p;
        atomicMin(&par[xb], gp);
        bk = gp;
    }
}

__device__ __forceinline__ void unite_l(int* par, int ka, int kb) {
    while (true) {
        ka = find_l(par, ka);
        kb = find_l(par, kb);
        if (ka == kb) return;
        if (ka > kb) { int t = ka; ka = kb; kb = t; }
        int old = atomicMin(&par[lkey2b(kb)], ka);
        if (old == kb) return;
        kb = old;
    }
}

__device__ __forceinline__ int bkey(int b, int m) {
    int base = ((b >> 6) << 8) + ((b & 63) << 1);
    int off = (m & 1) ? 0 : (m & 2) ? 1 : (m & 4) ? 128 : 129;
    return base + off;
}

// ------------------------------------------- local (per-tile) BKE CCL -----
__global__ __launch_bounds__(512) void ccl_local_bke(const float* __restrict__ prob,
                                                     int* __restrict__ Pb,
                                                     unsigned int* __restrict__ bnib) {
    __shared__ int bmask[NBLK];
    __shared__ int par[NBLK];
    const int tile_c = blockIdx.x * TILE;
    const int tile_r = blockIdx.y * TILE;
    const int tile_bj = blockIdx.x * BDIM;
    const int tile_bi = blockIdx.y * BDIM;
    const int tid = threadIdx.x;

    int nib[8];
    #pragma unroll
    for (int k = 0; k < 8; ++k) {
        int b = tid + 512 * k;
        int i = b >> 6, j = b & 63;
        const float* rp = prob + (size_t)(tile_r + 2 * i) * WW + tile_c + 2 * j;
        float2 t = *reinterpret_cast<const float2*>(rp);
        float2 bo = *reinterpret_cast<const float2*>(rp + WW);
        int m = (t.x > 0.5f ? 1 : 0) | (t.y > 0.5f ? 2 : 0) |
                (bo.x > 0.5f ? 4 : 0) | (bo.y > 0.5f ? 8 : 0);
        nib[k] = m;
        bmask[b] = m;
        par[b] = m ? bkey(b, m) : -1;
    }
    __syncthreads();

    #pragma unroll
    for (int k = 0; k < 8; ++k) {
        int m = nib[k];
        if (!m) continue;
        int b = tid + 512 * k;
        int i = b >> 6, j = b & 63;
        int mk = bkey(b, m);
        if (j > 0) {
            int wm = bmask[b - 1];
            if ((m & 0x5) && (wm & 0xA)) unite_l(par, mk, bkey(b - 1, wm));
        }
        if (i > 0) {
            int nm = bmask[b - BDIM];
            if ((m & 0x3) && (nm & 0xC)) unite_l(par, mk, bkey(b - BDIM, nm));
            if (j > 0) {
                int nwm = bmask[b - BDIM - 1];
                if ((m & 0x1) && (nwm & 0x8)) unite_l(par, mk, bkey(b - BDIM - 1, nwm));
            }
            if (j < BDIM - 1) {
                int nem = bmask[b - BDIM + 1];
                if ((m & 0x2) && (nem & 0x4)) unite_l(par, mk, bkey(b - BDIM + 1, nem));
            }
        }
    }
    __syncthreads();

    // flatten -> P_blk (one int per 2x2 block)
    #pragma unroll
    for (int k = 0; k < 8; ++k) {
        int b = tid + 512 * k;
        int i = b >> 6, j = b & 63;
        int m = nib[k];
        int val = -1;
        if (m) {
            int x = bkey(b, m);
            while (true) {
                int p = par[lkey2b(x)];
                if (p == x) break;
                x = p;
            }
            val = (tile_r + (x >> 7)) * WW + tile_c + (x & 127);
        }
        Pb[(size_t)(tile_bi + i) * BW + tile_bj + j] = val;
    }

    // pack bnib: thread w packs blocks 8w..8w+7 (one uint32 of 8 nibbles)
    {
        unsigned int word = 0;
        #pragma unroll
        for (int q = 0; q < 8; ++q)
            word |= (unsigned int)bmask[8 * tid + q] << (4 * q);
        int i = (8 * tid) >> 6;
        int wj = ((8 * tid) & 63) >> 3;
        bnib[(size_t)(tile_bi + i) * WPR + (tile_bj >> 3) + wj] = word;
    }
}

// -------------------------------------------- bit extraction helpers ------
__device__ __forceinline__ unsigned int ext01(unsigned int w) {
    unsigned int b = w & 0x33333333u;          // bits 0,1 of each nibble
    b = (b | (b >> 2)) & 0x0F0F0F0Fu;
    b = (b | (b >> 4)) & 0x00FF00FFu;
    b = (b | (b >> 8)) & 0x0000FFFFu;
    return b;
}
__device__ __forceinline__ unsigned int ext23(unsigned int w) { return ext01(w >> 2); }

// ---------------------- dedup'd cross-tile border unites (bitmask) --------
// Link set and run-start dedup identical to R9 (proven): for horizontal
// boundary row r, col c, j=c%128:
//   N  iff D&U      && (j==0   || !(D[c-1]&U[c-1]))
//   NW iff D&U[c-1] && (j==0   || (!U[c] && !D[c-1]))
//   NE iff D&U[c+1] && (j==127 || (!U[c] && !D[c+1]))
// Vertical family symmetric. One thread per 32-wide word.
__global__ void ccl_border(int* __restrict__ Pb,
                           const unsigned int* __restrict__ bnib) {
    int idx = blockIdx.x * 256 + threadIdx.x;
    if (idx >= BTHREADS) return;
    int bidx = idx >> 7;               // boundary 0..30
    int w    = idx & 127;              // word within boundary
    unsigned int edge0  = ((w & 3) == 0) ? 1u : 0u;
    unsigned int edge31 = ((w & 3) == 3) ? 0x80000000u : 0u;

    if (blockIdx.y == 0) {
        int r = (bidx + 1) * TILE;
        int bi_d = r >> 1, bi_u = bi_d - 1;
        int c0 = 32 * w;
        const unsigned int* rd = bnib + (size_t)bi_d * WPR;
        const unsigned int* ru = bnib + (size_t)bi_u * WPR;
        unsigned int D = ext01(rd[2 * w]) | (ext01(rd[2 * w + 1]) << 16);
        unsigned int U = ext23(ru[2 * w]) | (ext23(ru[2 * w + 1]) << 16);
        unsigned int dm1 = 0, um1 = 0, dp1 = 0, up1 = 0;
        if (c0 > 0) {
            dm1 = (rd[2 * w - 1] >> 29) & 1;   // nibble7 bit1
            um1 = (ru[2 * w - 1] >> 31) & 1;   // nibble7 bit3
        }
        if (c0 + 32 < WW) {
            dp1 = rd[2 * w + 2] & 1;           // nibble0 bit0
            up1 = (ru[2 * w + 2] >> 2) & 1;    // nibble0 bit2
        }
        unsigned int Dprev = (D << 1) | dm1, Uprev = (U << 1) | um1;
        unsigned int Dnext = (D >> 1) | (dp1 << 31), Unext = (U >> 1) | (up1 << 31);
        unsigned int Nm  = D & U     & (~(Dprev & Uprev) | edge0);
        unsigned int NWm = D & Uprev & ((~U & ~Dprev)    | edge0);
        unsigned int NEm = D & Unext & ((~U & ~Dnext)    | edge31);
        int baseD = r * WW + c0, baseU = baseD - WW;
        while (Nm)  { int k = __ffs(Nm)  - 1; Nm  &= Nm  - 1; unite_B(Pb, baseD + k, baseU + k); }
        while (NWm) { int k = __ffs(NWm) - 1; NWm &= NWm - 1; unite_B(Pb, baseD + k, baseU + k - 1); }
        while (NEm) { int k = __ffs(NEm) - 1; NEm &= NEm - 1; unite_B(Pb, baseD + k, baseU + k + 1); }
    } else {
        int c = (bidx + 1) * TILE;
        int bj_e = c >> 1, bj_w = bj_e - 1;
        int r0 = 32 * w;
        int bi0 = r0 >> 1;
        int we_idx = bj_e >> 3;            // nibble (bj_e&7)==0
        int ww_idx = bj_w >> 3;            // nibble (bj_w&7)==7
        unsigned int E = 0, W = 0;
        #pragma unroll
        for (int q = 0; q < 16; ++q) {
            unsigned int ne = bnib[(size_t)(bi0 + q) * WPR + we_idx] & 0xF;
            unsigned int nw = (bnib[(size_t)(bi0 + q) * WPR + ww_idx] >> 28) & 0xF;
            E |= (((ne >> 0) & 1) | (((ne >> 2) & 1) << 1)) << (2 * q);
            W |= (((nw >> 1) & 1) | (((nw >> 3) & 1) << 1)) << (2 * q);
        }
        unsigned int em1 = 0, wm1 = 0, ep1 = 0, wp1 = 0;
        if (r0 > 0) {
            em1 = (bnib[(size_t)(bi0 - 1) * WPR + we_idx] >> 2) & 1;        // bit2
            wm1 = (bnib[(size_t)(bi0 - 1) * WPR + ww_idx] >> 31) & 1;       // nib7 bit3
        }
        if (r0 + 32 < HH) {
            ep1 = bnib[(size_t)(bi0 + 16) * WPR + we_idx] & 1;              // bit0
            wp1 = (bnib[(size_t)(bi0 + 16) * WPR + ww_idx] >> 29) & 1;      // nib7 bit1
        }
        unsigned int Eprev = (E << 1) | em1, Wprev = (W << 1) | wm1;
        unsigned int Enext = (E >> 1) | (ep1 << 31), Wnext = (W >> 1) | (wp1 << 31);
        unsigned int Wl  = E & W     & (~(Eprev & Wprev) | edge0);
        unsigned int NWl = E & Wprev & ((~W & ~Eprev)    | edge0);
        unsigned int SWl = E & Wnext & ((~W & ~Enext)    | edge31);
        while (Wl)  { int k = __ffs(Wl)  - 1; Wl  &= Wl  - 1; unite_B(Pb, (r0 + k) * WW + c, (r0 + k) * WW + c - 1); }
        while (NWl) { int k = __ffs(NWl) - 1; NWl &= NWl - 1; unite_B(Pb, (r0 + k) * WW + c, (r0 + k - 1) * WW + c - 1); }
        while (SWl) { int k = __ffs(SWl) - 1; SWl &= SWl - 1; unite_B(Pb, (r0 + k) * WW + c, (r0 + k + 1) * WW + c - 1); }
    }
}

// --------------------------------- final: mask-gated resolve -> d_out -----
__device__ __forceinline__ int resolveB(const int* __restrict__ P, int x,
                                        int& ci, int& co) {
    if (x == ci) return co;
    int r = x;
    while (true) { int p = P[blkof(r)]; if (p == r) break; r = p; }
    ci = x; co = r + 1;
    return co;
}

__global__ void ccl_final8(const int* __restrict__ Pb,
                           const unsigned int* __restrict__ bnib,
                           int* __restrict__ out) {
    int t = blockIdx.x * 256 + threadIdx.x;
    int base = t * 8;
    int r = base >> 12, c0 = base & 4095;
    unsigned int nibs = bnib[(size_t)(r >> 1) * WPR + (c0 >> 4)] >> (4 * ((c0 >> 1) & 7));
    int4 pv = *reinterpret_cast<const int4*>(Pb + (size_t)(r >> 1) * BW + (c0 >> 1));
    const int* pvp = reinterpret_cast<const int*>(&pv);
    int rowsh = (r & 1) << 1;
    int lab[8];
    int ci = INT_MIN, co = 0;
    #pragma unroll
    for (int q = 0; q < 8; ++q) {
        int nb = (nibs >> (4 * (q >> 1))) & 0xF;
        int bit = (nb >> (rowsh | (q & 1))) & 1;
        lab[q] = bit ? resolveB(Pb, pvp[q >> 1], ci, co) : 0;
    }
    *reinterpret_cast<int4*>(out + base)     = make_int4(lab[0], lab[1], lab[2], lab[3]);
    *reinterpret_cast<int4*>(out + base + 4) = make_int4(lab[4], lab[5], lab[6], lab[7]);
}

// ---------------------------- fallback path (no ws): pixel-level ----------
__device__ __forceinline__ int find_root_g(int* P, int x) {
    while (true) {
        int p = P[x];
        if (p == x) return x;
        int gp = P[p];
        if (gp == p) return p;
        atomicMin(&P[x], gp);
        x = gp;
    }
}
__device__ __forceinline__ void unite_g(int* P, int a, int b) {
    while (true) {
        a = find_root_g(P, a);
        b = find_root_g(P, b);
        if (a == b) return;
        if (a > b) { int t = a; a = b; b = t; }
        int old = atomicMin(&P[b], a);
        if (old == b) return;
        b = old;
    }
}
__global__ void ccl_init_px(const float* __restrict__ prob, int* __restrict__ P) {
    int i = (blockIdx.x * blockDim.x + threadIdx.x) * 4;
    float4 v = *reinterpret_cast<const float4*>(prob + i);
    int4 o;
    o.x = (v.x > 0.5f) ? i : -1;
    o.y = (v.y > 0.5f) ? i + 1 : -1;
    o.z = (v.z > 0.5f) ? i + 2 : -1;
    o.w = (v.w > 0.5f) ? i + 3 : -1;
    *reinterpret_cast<int4*>(P + i) = o;
}
__global__ void ccl_merge_px(int* __restrict__ P) {
    int c = blockIdx.x * blockDim.x + threadIdx.x;
    int r = blockIdx.y * blockDim.y + threadIdx.y;
    int i = r * WW + c;
    if (P[i] < 0) return;
    if (c > 0 && P[i - 1] >= 0) unite_g(P, i, i - 1);
    if (r > 0) {
        int j = i - WW;
        if (P[j] >= 0) unite_g(P, i, j);
        else {
            if (c > 0      && P[j - 1] >= 0) unite_g(P, i, j - 1);
            if (c < WW - 1 && P[j + 1] >= 0) unite_g(P, i, j + 1);
        }
    }
}
__global__ void ccl_compress(int* __restrict__ P) {
    int i = blockIdx.x * blockDim.x + threadIdx.x;
    int x = P[i];
    if (x < 0) return;
    while (true) { int p = P[x]; if (p == x) break; x = p; }
    P[i] = x;
}
__global__ void ccl_convert(int* __restrict__ P) {
    int i = (blockIdx.x * blockDim.x + threadIdx.x) * 4;
    int4 v = *reinterpret_cast<const int4*>(P + i);
    v.x = (v.x < 0) ? 0 : v.x + 1;
    v.y = (v.y < 0) ? 0 : v.y + 1;
    v.z = (v.z < 0) ? 0 : v.z + 1;
    v.w = (v.w < 0) ? 0 : v.w + 1;
    *reinterpret_cast<int4*>(P + i) = v;
}

// ---------------------------------------------------------------- launch --
extern "C" void kernel_launch(void* const* d_in, const int* in_sizes, int n_in,
                              void* d_out, int out_size, void* d_ws, size_t ws_size,
                              hipStream_t stream) {
    const float* prob = (const float*)d_in[0];
    const size_t PB_BYTES = (size_t)(BW * BW) * sizeof(int);          // 16 MB
    const size_t BN_BYTES = (size_t)(BW * WPR) * sizeof(unsigned);    // 2 MB
    const bool have_ws = ws_size >= PB_BYTES + BN_BYTES;

    if (have_ws) {
        int* Pb = (int*)d_ws;
        unsigned int* bnib = (unsigned int*)((char*)d_ws + PB_BYTES);

        ccl_local_bke<<<dim3(WW / TILE, HH / TILE), dim3(512), 0, stream>>>(prob, Pb, bnib);
        ccl_border<<<dim3((BTHREADS + 255) / 256, 2), dim3(256), 0, stream>>>(Pb, bnib);
        ccl_final8<<<dim3(NPIX / 8 / 256), dim3(256), 0, stream>>>(Pb, bnib, (int*)d_out);
    } else {
        int* P = (int*)d_out;
        ccl_init_px<<<dim3(NPIX / 4 / 256), dim3(256), 0, stream>>>(prob, P);
        ccl_merge_px<<<dim3(WW / 64, HH / 4), dim3(64, 4), 0, stream>>>(P);
        ccl_compress<<<dim3(NPIX / 256), dim3(256), 0, stream>>>(P);
        ccl_convert<<<dim3(NPIX / 4 / 256), dim3(256), 0, stream>>>(P);
    }
}